// Round 15
// baseline (344.433 us; speedup 1.0000x reference)
//
#include <hip/hip_runtime.h>
#include <math.h>

#define NN 100000
#define NE 1600000
#define DF 256
#define HH 64
#define TT 4
#define GG 8
#define BN_EPS 1e-5f
#define NTOT (NE + NN)               // srcl entries incl. self-loops

#define BROWS 512                    // rows per bucket
#define NBK ((NN + BROWS - 1) / BROWS)   // 196
#define BCAP 10240                   // bucket capacity (mean 8192, sigma 90)
#define PCHUNK 1600
#define NPB (NE / PCHUNK)            // 1000

typedef __attribute__((ext_vector_type(8))) short short8v;
typedef __attribute__((ext_vector_type(4))) float f32x4;
typedef unsigned short ushort_t;
typedef unsigned int uint_t;

__device__ __forceinline__ void atomicMaxF(float* addr, float val) {
  if (val >= 0.f) atomicMax((int*)addr, __float_as_int(val));
  else            atomicMin((unsigned int*)addr, __float_as_uint(val));
}

__device__ __forceinline__ short f2bf(float f) {
  uint_t u = __float_as_uint(f);
  u += 0x7FFFu + ((u >> 16) & 1u);
  return (short)(u >> 16);
}
__device__ __forceinline__ float bf2f(uint_t u) { return __uint_as_float(u << 16); }
__device__ __forceinline__ float bfhi(uint_t u) { return __uint_as_float(u & 0xFFFF0000u); }

// ---------------- setup: W->bf16, stats=0, maxb=-inf, Bcnt=0 ----------------
__global__ void k_setup(const float* __restrict__ Wf, ushort_t* __restrict__ Wbf,
                        const float* __restrict__ Wc, ushort_t* __restrict__ Wbf2,
                        float* __restrict__ stats, float* __restrict__ maxb,
                        int* __restrict__ Bcnt) {
  int i = blockIdx.x * 256 + threadIdx.x;       // 80 blocks x 256 = 20480
  if (i < DF * HH) Wbf[i] = (ushort_t)f2bf(Wf[i]);
  else {
    int j = i - DF * HH;
    if (j < HH * HH) Wbf2[j] = (ushort_t)f2bf(Wc[j]);
  }
  if (i < 512) stats[i] = 0.f;
  if (i < 64)  maxb[i]  = -INFINITY;
  if (i < NBK) Bcnt[i]  = 0;
}

// ---------------- GEMM1 (MFMA bf16): h1 = x @ W_first + b (bf16 out), + BN stats ----
// W-frags live in LDS (frag-packed, linear 16B/lane reads = conflict-free b128),
// freeing ~128 VGPRs -> ~5 waves/SIMD for HBM latency hiding on the x stream.
__global__ __launch_bounds__(256) void k_gemm1_mfma(
    const float* __restrict__ x, const ushort_t* __restrict__ Wbf,
    const float* __restrict__ b, ushort_t* __restrict__ h1,
    float* __restrict__ stats) {
  __shared__ short8v Wf[32][64];                // 32 KB
  const int lane = threadIdx.x & 63;
  const int li = lane & 15;
  const int lh = lane >> 4;

  for (int i = threadIdx.x; i < 32 * 64; i += 256) {
    int fi = i >> 6, le = i & 63;
    int s = fi >> 2, ct = fi & 3;
    int lli = le & 15, llh = le >> 4;
    short8v v;
#pragma unroll
    for (int e = 0; e < 8; ++e)
      v[e] = (short)Wbf[(32 * s + 8 * llh + e) * HH + ct * 16 + lli];
    Wf[fi][le] = v;
  }
  __syncthreads();

  const int gw = (blockIdx.x * 256 + (int)threadIdx.x) >> 6;
  const int nw = (gridDim.x * 256) >> 6;

  float bias[4];
#pragma unroll
  for (int ct = 0; ct < 4; ++ct) bias[ct] = b[ct * 16 + li];

  float ps[4] = {0.f, 0.f, 0.f, 0.f}, pss[4] = {0.f, 0.f, 0.f, 0.f};

  for (int t = gw; t < NN / 16; t += nw) {
    const float* xb = x + (size_t)(t * 16 + li) * DF + 8 * lh;
    f32x4 acc[4];
#pragma unroll
    for (int ct = 0; ct < 4; ++ct) acc[ct] = (f32x4){0.f, 0.f, 0.f, 0.f};

#pragma unroll
    for (int s = 0; s < 8; ++s) {
      float4 a0 = *(const float4*)(xb + 32 * s);
      float4 a1 = *(const float4*)(xb + 32 * s + 4);
      short8v af;
      af[0] = f2bf(a0.x); af[1] = f2bf(a0.y); af[2] = f2bf(a0.z); af[3] = f2bf(a0.w);
      af[4] = f2bf(a1.x); af[5] = f2bf(a1.y); af[6] = f2bf(a1.z); af[7] = f2bf(a1.w);
#pragma unroll
      for (int ct = 0; ct < 4; ++ct)
        acc[ct] = __builtin_amdgcn_mfma_f32_16x16x32_bf16(af, Wf[4 * s + ct][lane], acc[ct], 0, 0, 0);
    }

    ushort_t* hb = h1 + (size_t)t * 16 * HH;
#pragma unroll
    for (int ct = 0; ct < 4; ++ct) {
#pragma unroll
      for (int r = 0; r < 4; ++r) {
        float h = acc[ct][r] + bias[ct];
        hb[(lh * 4 + r) * HH + ct * 16 + li] = (ushort_t)f2bf(h);
        ps[ct] += h; pss[ct] += h * h;
      }
    }
  }

#pragma unroll
  for (int ct = 0; ct < 4; ++ct) {
    ps[ct]  += __shfl_xor(ps[ct], 16);  ps[ct]  += __shfl_xor(ps[ct], 32);
    pss[ct] += __shfl_xor(pss[ct], 16); pss[ct] += __shfl_xor(pss[ct], 32);
  }
  if (lane < 16) {
#pragma unroll
    for (int ct = 0; ct < 4; ++ct) {
      atomicAdd(&stats[ct * 16 + lane], ps[ct]);
      atomicAdd(&stats[HH + ct * 16 + lane], pss[ct]);
    }
  }
}

// ---------------- fused: BN-finalize (in-block) + normalize(h1)+ReLU;
//                  np0 + pool via 5th MFMA tile; g = f @ W_conv (bf16 out) ----------------
__global__ __launch_bounds__(256) void k_norm_gemm2(
    const ushort_t* __restrict__ h1, const float* __restrict__ stats,
    const float* __restrict__ gamma, const float* __restrict__ beta,
    const float* __restrict__ Wl0, const float* __restrict__ bl0,
    const int* __restrict__ batch, const ushort_t* __restrict__ Wbf2,
    float* __restrict__ node_pred, float* __restrict__ maxbuf,
    ushort_t* __restrict__ g) {
  __shared__ float lmax[GG * TT];
  __shared__ float abl[128];
  if (threadIdx.x < GG * TT) lmax[threadIdx.x] = -INFINITY;
  if (threadIdx.x < 64) {
    int c = threadIdx.x;
    float mu  = stats[c] * (1.f / NN);
    float var = stats[HH + c] * (1.f / NN) - mu * mu;
    float a = gamma[c] * rsqrtf(var + BN_EPS);
    abl[c] = a;
    abl[HH + c] = beta[c] - mu * a;
  }
  __syncthreads();

  const int lane = threadIdx.x & 63;
  const int li = lane & 15;
  const int lh = lane >> 4;
  const int gw = (blockIdx.x * 256 + (int)threadIdx.x) >> 6;
  const int nw = (gridDim.x * 256) >> 6;

  short8v bfr[2][4];
#pragma unroll
  for (int s = 0; s < 2; ++s)
#pragma unroll
    for (int ct = 0; ct < 4; ++ct)
#pragma unroll
      for (int e = 0; e < 8; ++e)
        bfr[s][ct][e] = (short)Wbf2[(32 * s + 8 * lh + e) * HH + ct * 16 + li];

  short8v bhd[2];
#pragma unroll
  for (int s = 0; s < 2; ++s)
#pragma unroll
    for (int e = 0; e < 8; ++e)
      bhd[s][e] = (li < TT) ? f2bf(Wl0[(32 * s + 8 * lh + e) * TT + li]) : (short)0;

  const float4 sa0 = *(const float4*)(abl + 8 * lh);
  const float4 sa1 = *(const float4*)(abl + 8 * lh + 4);
  const float4 sb0 = *(const float4*)(abl + HH + 8 * lh);
  const float4 sb1 = *(const float4*)(abl + HH + 8 * lh + 4);
  const float4 ta0 = *(const float4*)(abl + 32 + 8 * lh);
  const float4 ta1 = *(const float4*)(abl + 32 + 8 * lh + 4);
  const float4 tb0 = *(const float4*)(abl + HH + 32 + 8 * lh);
  const float4 tb1 = *(const float4*)(abl + HH + 32 + 8 * lh + 4);
  const float blv = (li < TT) ? bl0[li] : 0.f;

  for (int t = gw; t < NN / 16; t += nw) {
    const ushort_t* hb = h1 + (size_t)(t * 16 + li) * HH + 8 * lh;
    uint4 xa = *(const uint4*)(hb);
    uint4 xc = *(const uint4*)(hb + 32);

    short8v af0, af1;
    af0[0] = f2bf(fmaxf(fmaf(sa0.x, bf2f(xa.x), sb0.x), 0.f));
    af0[1] = f2bf(fmaxf(fmaf(sa0.y, bfhi(xa.x), sb0.y), 0.f));
    af0[2] = f2bf(fmaxf(fmaf(sa0.z, bf2f(xa.y), sb0.z), 0.f));
    af0[3] = f2bf(fmaxf(fmaf(sa0.w, bfhi(xa.y), sb0.w), 0.f));
    af0[4] = f2bf(fmaxf(fmaf(sa1.x, bf2f(xa.z), sb1.x), 0.f));
    af0[5] = f2bf(fmaxf(fmaf(sa1.y, bfhi(xa.z), sb1.y), 0.f));
    af0[6] = f2bf(fmaxf(fmaf(sa1.z, bf2f(xa.w), sb1.z), 0.f));
    af0[7] = f2bf(fmaxf(fmaf(sa1.w, bfhi(xa.w), sb1.w), 0.f));
    af1[0] = f2bf(fmaxf(fmaf(ta0.x, bf2f(xc.x), tb0.x), 0.f));
    af1[1] = f2bf(fmaxf(fmaf(ta0.y, bfhi(xc.x), tb0.y), 0.f));
    af1[2] = f2bf(fmaxf(fmaf(ta0.z, bf2f(xc.y), tb0.z), 0.f));
    af1[3] = f2bf(fmaxf(fmaf(ta0.w, bfhi(xc.y), tb0.w), 0.f));
    af1[4] = f2bf(fmaxf(fmaf(ta1.x, bf2f(xc.z), tb1.x), 0.f));
    af1[5] = f2bf(fmaxf(fmaf(ta1.y, bfhi(xc.z), tb1.y), 0.f));
    af1[6] = f2bf(fmaxf(fmaf(ta1.z, bf2f(xc.w), tb1.z), 0.f));
    af1[7] = f2bf(fmaxf(fmaf(ta1.w, bfhi(xc.w), tb1.w), 0.f));

    f32x4 acc[4], acch;
#pragma unroll
    for (int ct = 0; ct < 4; ++ct) {
      acc[ct] = (f32x4){0.f, 0.f, 0.f, 0.f};
      acc[ct] = __builtin_amdgcn_mfma_f32_16x16x32_bf16(af0, bfr[0][ct], acc[ct], 0, 0, 0);
      acc[ct] = __builtin_amdgcn_mfma_f32_16x16x32_bf16(af1, bfr[1][ct], acc[ct], 0, 0, 0);
    }
    acch = (f32x4){0.f, 0.f, 0.f, 0.f};
    acch = __builtin_amdgcn_mfma_f32_16x16x32_bf16(af0, bhd[0], acch, 0, 0, 0);
    acch = __builtin_amdgcn_mfma_f32_16x16x32_bf16(af1, bhd[1], acch, 0, 0, 0);

    ushort_t* gb = g + (size_t)t * 16 * HH;
#pragma unroll
    for (int ct = 0; ct < 4; ++ct)
#pragma unroll
      for (int r = 0; r < 4; ++r)
        gb[(lh * 4 + r) * HH + ct * 16 + li] = (ushort_t)f2bf(acc[ct][r]);

    if (li < TT) {
#pragma unroll
      for (int r = 0; r < 4; ++r) {
        int row = t * 16 + lh * 4 + r;
        float np = acch[r] + blv;
        atomicMaxF(&lmax[batch[row] * TT + li], np);
        node_pred[(size_t)row * TT + li] = np;
      }
    }
  }
  __syncthreads();
  if (threadIdx.x < GG * TT) atomicMaxF(&maxbuf[threadIdx.x], lmax[threadIdx.x]);
}

// ---------------- fused: BN-finalize (in-block) + normalize+ReLU + head + max-pool ----
__global__ __launch_bounds__(256) void k_norm_np(
    const ushort_t* __restrict__ hin, const float* __restrict__ stats,
    const float* __restrict__ gamma, const float* __restrict__ beta,
    const float* __restrict__ Wlin, const float* __restrict__ blin,
    const int* __restrict__ batch, float* __restrict__ node_pred,
    float* __restrict__ maxbuf, int rpb) {
  __shared__ float lmax[GG * TT];
  __shared__ float abl[128];
  if (threadIdx.x < GG * TT) lmax[threadIdx.x] = -INFINITY;
  if (threadIdx.x < 64) {
    int c = threadIdx.x;
    float mu  = stats[c] * (1.f / NN);
    float var = stats[HH + c] * (1.f / NN) - mu * mu;
    float a = gamma[c] * rsqrtf(var + BN_EPS);
    abl[c] = a;
    abl[HH + c] = beta[c] - mu * a;
  }
  __syncthreads();

  const int lane = threadIdx.x & 63;
  const int wid  = threadIdx.x >> 6;
  const float a  = abl[lane];
  const float b2 = abl[HH + lane];
  const float4 w = ((const float4*)Wlin)[lane];
  const float4 bl = *(const float4*)blin;
  int r0 = blockIdx.x * rpb;
  int r1 = min(r0 + rpb, NN);

  for (int r = r0 + wid; r < r1; r += 4) {
    float h = bf2f(hin[(size_t)r * HH + lane]);
    float f = fmaxf(fmaf(a, h, b2), 0.f);
    float p0 = f * w.x, p1 = f * w.y, p2 = f * w.z, p3 = f * w.w;
#pragma unroll
    for (int off = 32; off; off >>= 1) {
      p0 += __shfl_xor(p0, off);
      p1 += __shfl_xor(p1, off);
      p2 += __shfl_xor(p2, off);
      p3 += __shfl_xor(p3, off);
    }
    if (lane == 0) {
      float4 np;
      np.x = p0 + bl.x; np.y = p1 + bl.y; np.z = p2 + bl.z; np.w = p3 + bl.w;
      int g = batch[r];
      atomicMaxF(&lmax[g * TT + 0], np.x);
      atomicMaxF(&lmax[g * TT + 1], np.y);
      atomicMaxF(&lmax[g * TT + 2], np.z);
      atomicMaxF(&lmax[g * TT + 3], np.w);
      float4* op = (float4*)(node_pred + (size_t)r * TT);
      float4 o = *op;
      np.x += o.x; np.y += o.y; np.z += o.z; np.w += o.w;
      *op = np;
    }
  }
  __syncthreads();
  if (threadIdx.x < GG * TT) atomicMaxF(&maxbuf[threadIdx.x], lmax[threadIdx.x]);
}

// ---------------- bucketed CSR build ----------------
__global__ __launch_bounds__(256) void k_part(
    const int* __restrict__ ei, int* __restrict__ Bcnt,
    uint2* __restrict__ ebuf) {
  __shared__ int hist[256], start[256], cnt[256], gbase[256];
  __shared__ int ssrc[PCHUNK], sdst[PCHUNK];
  const int t = threadIdx.x;
  hist[t] = 0; cnt[t] = 0;
  __syncthreads();
  const int e0 = blockIdx.x * PCHUNK;
  for (int i = t; i < PCHUNK; i += 256)
    atomicAdd(&hist[ei[NE + e0 + i] >> 9], 1);
  __syncthreads();
  int v = hist[t];
  start[t] = v;
  __syncthreads();
  for (int off = 1; off < 256; off <<= 1) {
    int u = (t >= off) ? start[t - off] : 0;
    __syncthreads();
    start[t] += u;
    __syncthreads();
  }
  int incl = start[t];
  __syncthreads();
  start[t] = incl - v;                       // exclusive
  if (v > 0) gbase[t] = atomicAdd(&Bcnt[t], v);
  __syncthreads();
  for (int i = t; i < PCHUNK; i += 256) {
    int src = ei[e0 + i];
    int dst = ei[NE + e0 + i];
    int b = dst >> 9;
    int p = start[b] + atomicAdd(&cnt[b], 1);
    ssrc[p] = src; sdst[p] = dst;
  }
  __syncthreads();
  for (int i = t; i < PCHUNK; i += 256) {
    int dst = sdst[i];
    int b = dst >> 9;
    uint2 pr; pr.x = (uint_t)ssrc[i]; pr.y = (uint_t)dst;
    ebuf[(size_t)b * BCAP + gbase[b] + (i - start[b])] = pr;
  }
}

__global__ void k_bscan(const int* __restrict__ Bcnt, int* __restrict__ Bbase) {
  __shared__ int s[256];
  int t = threadIdx.x;
  int v = 0;
  if (t < NBK) {
    int rows = min(BROWS, NN - t * BROWS);
    v = Bcnt[t] + rows;
  }
  s[t] = v;
  __syncthreads();
  for (int off = 1; off < 256; off <<= 1) {
    int u = (t >= off) ? s[t - off] : 0;
    __syncthreads();
    s[t] += u;
    __syncthreads();
  }
  if (t < NBK) Bbase[t] = s[t] - v;
}

__global__ __launch_bounds__(256) void k_fill2(
    const int* __restrict__ Bcnt, const int* __restrict__ Bbase,
    const uint2* __restrict__ ebuf, int* __restrict__ rowstart,
    int* __restrict__ srcl) {
  __shared__ int cnt[BROWS];
  __shared__ int ssum[256];
  const int b = blockIdx.x;
  const int r0 = b * BROWS;
  const int nrows = min(BROWS, NN - r0);
  const int ne = Bcnt[b];
  const int base = Bbase[b];
  const uint2* eb = ebuf + (size_t)b * BCAP;
  const int t = threadIdx.x;

  cnt[2 * t] = (2 * t < nrows) ? 1 : 0;
  cnt[2 * t + 1] = (2 * t + 1 < nrows) ? 1 : 0;
  __syncthreads();
  for (int j = t; j < ne; j += 256)
    atomicAdd(&cnt[(int)eb[j].y - r0], 1);
  __syncthreads();

  int a0 = cnt[2 * t], a1 = cnt[2 * t + 1];
  ssum[t] = a0 + a1;
  __syncthreads();
  for (int off = 1; off < 256; off <<= 1) {
    int u = (t >= off) ? ssum[t - off] : 0;
    __syncthreads();
    ssum[t] += u;
    __syncthreads();
  }
  int e0 = base + ssum[t] - (a0 + a1);
  int e1 = e0 + a0;
  __syncthreads();
  if (2 * t < nrows)     { rowstart[r0 + 2 * t] = e0;     srcl[e0] = r0 + 2 * t; }
  if (2 * t + 1 < nrows) { rowstart[r0 + 2 * t + 1] = e1; srcl[e1] = r0 + 2 * t + 1; }
  cnt[2 * t] = e0 + 1;
  cnt[2 * t + 1] = e1 + 1;
  __syncthreads();
  for (int j = t; j < ne; j += 256) {
    uint2 pr = eb[j];
    int p = atomicAdd(&cnt[(int)pr.y - r0], 1);
    srcl[p] = (int)pr.x;
  }
}

// ---------------- gather: h2[r] = b + sum_{srcl entries incl self} g[s] ----------------
#define RF(x) __builtin_amdgcn_readfirstlane(x)
#define GLD(V, I) asm volatile("global_load_ushort %0, %1, %2" \
    : "=v"(V) : "v"(voff), "s"(g + (size_t)(I) * HH) : "memory")
#define WAIT16 do { asm volatile("s_waitcnt vmcnt(16)" ::: "memory"); \
    __builtin_amdgcn_sched_barrier(0); } while (0)
#define WAIT0 do { asm volatile("s_waitcnt vmcnt(0)" ::: "memory"); \
    __builtin_amdgcn_sched_barrier(0); } while (0)
#define ISSUE16(P, EB) do { \
  int j0 = RF(srcl[(EB) + 0]),  j1 = RF(srcl[(EB) + 1]); \
  int j2 = RF(srcl[(EB) + 2]),  j3 = RF(srcl[(EB) + 3]); \
  int j4 = RF(srcl[(EB) + 4]),  j5 = RF(srcl[(EB) + 5]); \
  int j6 = RF(srcl[(EB) + 6]),  j7 = RF(srcl[(EB) + 7]); \
  int j8 = RF(srcl[(EB) + 8]),  j9 = RF(srcl[(EB) + 9]); \
  int j10 = RF(srcl[(EB) + 10]), j11 = RF(srcl[(EB) + 11]); \
  int j12 = RF(srcl[(EB) + 12]), j13 = RF(srcl[(EB) + 13]); \
  int j14 = RF(srcl[(EB) + 14]), j15 = RF(srcl[(EB) + 15]); \
  GLD(P##0, j0);  GLD(P##1, j1);  GLD(P##2, j2);  GLD(P##3, j3); \
  GLD(P##4, j4);  GLD(P##5, j5);  GLD(P##6, j6);  GLD(P##7, j7); \
  GLD(P##8, j8);  GLD(P##9, j9);  GLD(P##10, j10); GLD(P##11, j11); \
  GLD(P##12, j12); GLD(P##13, j13); GLD(P##14, j14); GLD(P##15, j15); \
} while (0)
#define CJ(V, EI) do { \
  if ((EI) == nb) { \
    h2[(size_t)cur * HH + lane] = (ushort_t)f2bf(acc); ps += acc; pss += acc * acc; \
    cur++; nb = __builtin_amdgcn_readlane(rsv, cur - wra); acc = bc; \
  } \
  acc += bf2f(V); } while (0)
#define CONS16(P, EB) do { \
  CJ(P##0, (EB) + 0);  CJ(P##1, (EB) + 1);  CJ(P##2, (EB) + 2);  CJ(P##3, (EB) + 3); \
  CJ(P##4, (EB) + 4);  CJ(P##5, (EB) + 5);  CJ(P##6, (EB) + 6);  CJ(P##7, (EB) + 7); \
  CJ(P##8, (EB) + 8);  CJ(P##9, (EB) + 9);  CJ(P##10, (EB) + 10); CJ(P##11, (EB) + 11); \
  CJ(P##12, (EB) + 12); CJ(P##13, (EB) + 13); CJ(P##14, (EB) + 14); CJ(P##15, (EB) + 15); \
} while (0)

__global__ __launch_bounds__(256) void k_gather(
    const ushort_t* __restrict__ g, const int* __restrict__ rowstart,
    const int* __restrict__ srcl, const float* __restrict__ bias,
    ushort_t* __restrict__ h2, float* __restrict__ stats) {
  const int lane = threadIdx.x & 63;
  const int wid  = threadIdx.x >> 6;
  const float bc = bias[lane];
  const uint_t voff = lane * 2;
  const int wra = (blockIdx.x * 4 + wid) * 8;

  int ridx = wra + 1 + lane;
  int rsv = (ridx < NN) ? rowstart[ridx] : NTOT;

  int e    = RF(rowstart[wra]);
  int eEnd = __builtin_amdgcn_readlane(rsv, 7);
  int cur  = wra;
  int nb   = __builtin_amdgcn_readlane(rsv, 0);
  float acc = bc, ps = 0.f, pss = 0.f;

  uint_t A0, A1, A2, A3, A4, A5, A6, A7, A8, A9, A10, A11, A12, A13, A14, A15;
  uint_t B0, B1, B2, B3, B4, B5, B6, B7, B8, B9, B10, B11, B12, B13, B14, B15;

  int n = (eEnd - e) >> 4;
  if (n > 0) {
    int pend = e;
    ISSUE16(A, e); e += 16; n--;
    while (n >= 2) {
      int eb = e;
      ISSUE16(B, e); e += 16; n--;
      WAIT16; CONS16(A, pend); pend = eb;
      int ea = e;
      ISSUE16(A, e); e += 16; n--;
      WAIT16; CONS16(B, pend); pend = ea;
    }
    if (n == 1) {
      int eb = e;
      ISSUE16(B, e); e += 16;
      WAIT16; CONS16(A, pend); pend = eb;
      WAIT0;  CONS16(B, pend);
    } else {
      WAIT0;  CONS16(A, pend);
    }
  }
  for (; e < eEnd; ++e) {
    if (e == nb) {
      h2[(size_t)cur * HH + lane] = (ushort_t)f2bf(acc); ps += acc; pss += acc * acc;
      cur++; nb = __builtin_amdgcn_readlane(rsv, cur - wra); acc = bc;
    }
    int i = RF(srcl[e]);
    acc += bf2f(g[(size_t)i * HH + lane]);
  }
  h2[(size_t)cur * HH + lane] = (ushort_t)f2bf(acc); ps += acc; pss += acc * acc;

  __shared__ float sred[4][128];
  sred[wid][lane] = ps;
  sred[wid][64 + lane] = pss;
  __syncthreads();
  if (wid == 0) {
    float s0 = sred[0][lane] + sred[1][lane] + sred[2][lane] + sred[3][lane];
    float q0 = sred[0][64 + lane] + sred[1][64 + lane] + sred[2][64 + lane] + sred[3][64 + lane];
    atomicAdd(&stats[lane], s0);
    atomicAdd(&stats[HH + lane], q0);
  }
}

// ---------------- final: wsi = max0 + max1 ----------------
__global__ void k_wsi(const float* __restrict__ m0, const float* __restrict__ m1,
                      float* __restrict__ out) {
  int i = threadIdx.x;
  out[i] = m0[i] + m1[i];
}

extern "C" void kernel_launch(void* const* d_in, const int* in_sizes, int n_in,
                              void* d_out, int out_size, void* d_ws, size_t ws_size,
                              hipStream_t stream) {
  const float* x    = (const float*)d_in[0];
  const int*   ei   = (const int*)d_in[1];
  const int*   bat  = (const int*)d_in[2];
  const float* Wf   = (const float*)d_in[3];
  const float* bf   = (const float*)d_in[4];
  const float* g1   = (const float*)d_in[5];
  const float* be1  = (const float*)d_in[6];
  const float* Wl0  = (const float*)d_in[7];
  const float* bl0  = (const float*)d_in[8];
  const float* Wc   = (const float*)d_in[9];
  const float* bc   = (const float*)d_in[10];
  const float* g2   = (const float*)d_in[11];
  const float* be2  = (const float*)d_in[12];
  const float* Wl1  = (const float*)d_in[13];
  const float* bl1  = (const float*)d_in[14];

  float* out   = (float*)d_out;
  float* wsi   = out;                 // [8,4]
  float* npred = out + GG * TT;       // [N,4]

  ushort_t* h2bf   = (ushort_t*)d_ws;                 // N*H bf16 (h2)
  ushort_t* h1bf   = h2bf + (size_t)NN * HH;          // N*H bf16 (h1)
  ushort_t* gbf    = h1bf + (size_t)NN * HH;          // N*H bf16 (g)
  float*    stats1 = (float*)(gbf + (size_t)NN * HH); // 256
  float*    stats2 = stats1 + 256;                    // 256
  float*    maxb   = stats2 + 256;                    // 64
  int*      rowstart = (int*)(maxb + 64);             // N
  int*      Bcnt     = rowstart + NN;                 // 256
  int*      Bbase    = Bcnt + 256;                    // 256
  int*      srcl     = Bbase + 256;                   // NE+NN (self-loops)
  uint2*    ebuf     = (uint2*)(srcl + NTOT);         // NBK*BCAP pairs (16 MB)
  ushort_t* Wbf      = (ushort_t*)(ebuf + (size_t)NBK * BCAP);  // DF*HH
  ushort_t* Wbf2     = Wbf + DF * HH;                 // HH*HH

  // setup + bucketed CSR build
  k_setup<<<dim3(80), dim3(256), 0, stream>>>(Wf, Wbf, Wc, Wbf2, stats1, maxb, Bcnt);
  k_part<<<dim3(NPB), dim3(256), 0, stream>>>(ei, Bcnt, ebuf);
  k_bscan<<<dim3(1), dim3(256), 0, stream>>>(Bcnt, Bbase);
  k_fill2<<<dim3(NBK), dim3(256), 0, stream>>>(Bcnt, Bbase, ebuf, rowstart, srcl);

  // Layer 0: GEMM + stats (W in LDS for occupancy)
  k_gemm1_mfma<<<dim3(1024), dim3(256), 0, stream>>>(x, Wbf, bf, h1bf, stats1);
  k_norm_gemm2<<<dim3(512), dim3(256), 0, stream>>>(
      h1bf, stats1, g1, be1, Wl0, bl0, bat, Wbf2, npred, maxb, gbf);

  // Layer 1: h2 = b + g + A.g (2-deep pipelined flat-stream gather)
  k_gather<<<dim3(NN / 32), dim3(256), 0, stream>>>(
      gbf, rowstart, srcl, bc, h2bf, stats2);
  k_norm_np<<<dim3(512), dim3(256), 0, stream>>>(
      h2bf, stats2, g2, be2, Wl1, bl1, bat, npred, maxb + 32, (NN + 511) / 512);

  k_wsi<<<dim3(1), dim3(32), 0, stream>>>(maxb, maxb + 32, wsi);
}

// Round 16
// 295.172 us; speedup vs baseline: 1.1669x; 1.1669x over previous
//
#include <hip/hip_runtime.h>
#include <math.h>

#define NN 100000
#define NE 1600000
#define DF 256
#define HH 64
#define TT 4
#define GG 8
#define BN_EPS 1e-5f
#define NTOT (NE + NN)               // srcl entries incl. self-loops

#define BROWS 512                    // rows per bucket
#define NBK ((NN + BROWS - 1) / BROWS)   // 196
#define BCAP 10240                   // bucket capacity (mean 8192, sigma 90)
#define PCHUNK 1600
#define NPB (NE / PCHUNK)            // 1000

typedef __attribute__((ext_vector_type(8))) short short8v;
typedef __attribute__((ext_vector_type(4))) float f32x4;
typedef unsigned short ushort_t;
typedef unsigned int uint_t;

__device__ __forceinline__ void atomicMaxF(float* addr, float val) {
  if (val >= 0.f) atomicMax((int*)addr, __float_as_int(val));
  else            atomicMin((unsigned int*)addr, __float_as_uint(val));
}

__device__ __forceinline__ short f2bf(float f) {
  uint_t u = __float_as_uint(f);
  u += 0x7FFFu + ((u >> 16) & 1u);
  return (short)(u >> 16);
}
__device__ __forceinline__ float bf2f(uint_t u) { return __uint_as_float(u << 16); }
__device__ __forceinline__ float bfhi(uint_t u) { return __uint_as_float(u & 0xFFFF0000u); }

// ---------------- setup: W->bf16, stats=0, maxb=-inf, Bcnt=0 ----------------
__global__ void k_setup(const float* __restrict__ Wf, ushort_t* __restrict__ Wbf,
                        const float* __restrict__ Wc, ushort_t* __restrict__ Wbf2,
                        float* __restrict__ stats, float* __restrict__ maxb,
                        int* __restrict__ Bcnt) {
  int i = blockIdx.x * 256 + threadIdx.x;       // 80 blocks x 256 = 20480
  if (i < DF * HH) Wbf[i] = (ushort_t)f2bf(Wf[i]);
  else {
    int j = i - DF * HH;
    if (j < HH * HH) Wbf2[j] = (ushort_t)f2bf(Wc[j]);
  }
  if (i < 512) stats[i] = 0.f;
  if (i < 64)  maxb[i]  = -INFINITY;
  if (i < NBK) Bcnt[i]  = 0;
}

// ---------------- GEMM1 (MFMA bf16): h1 = x @ W_first + b (bf16 out), + BN stats ----
// W in REGISTERS (R14 config — proven; LDS variant regressed: ds_read_b128 on
// every MFMA's critical path, R15 post-mortem).
__global__ __launch_bounds__(256, 2) void k_gemm1_mfma(
    const float* __restrict__ x, const ushort_t* __restrict__ Wbf,
    const float* __restrict__ b, ushort_t* __restrict__ h1,
    float* __restrict__ stats) {
  const int lane = threadIdx.x & 63;
  const int li = lane & 15;
  const int lh = lane >> 4;
  const int gw = (blockIdx.x * 256 + (int)threadIdx.x) >> 6;
  const int nw = (gridDim.x * 256) >> 6;

  short8v bf[8][4];
#pragma unroll
  for (int s = 0; s < 8; ++s)
#pragma unroll
    for (int ct = 0; ct < 4; ++ct)
#pragma unroll
      for (int e = 0; e < 8; ++e)
        bf[s][ct][e] = (short)Wbf[(32 * s + 8 * lh + e) * HH + ct * 16 + li];

  float bias[4];
#pragma unroll
  for (int ct = 0; ct < 4; ++ct) bias[ct] = b[ct * 16 + li];

  float ps[4] = {0.f, 0.f, 0.f, 0.f}, pss[4] = {0.f, 0.f, 0.f, 0.f};

  for (int t = gw; t < NN / 16; t += nw) {
    const float* xb = x + (size_t)(t * 16 + li) * DF + 8 * lh;
    f32x4 acc[4];
#pragma unroll
    for (int ct = 0; ct < 4; ++ct) acc[ct] = (f32x4){0.f, 0.f, 0.f, 0.f};

#pragma unroll
    for (int s = 0; s < 8; ++s) {
      float4 a0 = *(const float4*)(xb + 32 * s);
      float4 a1 = *(const float4*)(xb + 32 * s + 4);
      short8v af;
      af[0] = f2bf(a0.x); af[1] = f2bf(a0.y); af[2] = f2bf(a0.z); af[3] = f2bf(a0.w);
      af[4] = f2bf(a1.x); af[5] = f2bf(a1.y); af[6] = f2bf(a1.z); af[7] = f2bf(a1.w);
#pragma unroll
      for (int ct = 0; ct < 4; ++ct)
        acc[ct] = __builtin_amdgcn_mfma_f32_16x16x32_bf16(af, bf[s][ct], acc[ct], 0, 0, 0);
    }

    ushort_t* hb = h1 + (size_t)t * 16 * HH;
#pragma unroll
    for (int ct = 0; ct < 4; ++ct) {
#pragma unroll
      for (int r = 0; r < 4; ++r) {
        float h = acc[ct][r] + bias[ct];
        hb[(lh * 4 + r) * HH + ct * 16 + li] = (ushort_t)f2bf(h);
        ps[ct] += h; pss[ct] += h * h;
      }
    }
  }

#pragma unroll
  for (int ct = 0; ct < 4; ++ct) {
    ps[ct]  += __shfl_xor(ps[ct], 16);  ps[ct]  += __shfl_xor(ps[ct], 32);
    pss[ct] += __shfl_xor(pss[ct], 16); pss[ct] += __shfl_xor(pss[ct], 32);
  }
  if (lane < 16) {
#pragma unroll
    for (int ct = 0; ct < 4; ++ct) {
      atomicAdd(&stats[ct * 16 + lane], ps[ct]);
      atomicAdd(&stats[HH + ct * 16 + lane], pss[ct]);
    }
  }
}

// ---------------- fused: BN-finalize (in-block) + normalize(h1)+ReLU;
//                  np0 + pool via 5th MFMA tile; g = f @ W_conv (bf16 out) ----------------
__global__ __launch_bounds__(256) void k_norm_gemm2(
    const ushort_t* __restrict__ h1, const float* __restrict__ stats,
    const float* __restrict__ gamma, const float* __restrict__ beta,
    const float* __restrict__ Wl0, const float* __restrict__ bl0,
    const int* __restrict__ batch, const ushort_t* __restrict__ Wbf2,
    float* __restrict__ node_pred, float* __restrict__ maxbuf,
    ushort_t* __restrict__ g) {
  __shared__ float lmax[GG * TT];
  __shared__ float abl[128];
  if (threadIdx.x < GG * TT) lmax[threadIdx.x] = -INFINITY;
  if (threadIdx.x < 64) {
    int c = threadIdx.x;
    float mu  = stats[c] * (1.f / NN);
    float var = stats[HH + c] * (1.f / NN) - mu * mu;
    float a = gamma[c] * rsqrtf(var + BN_EPS);
    abl[c] = a;
    abl[HH + c] = beta[c] - mu * a;
  }
  __syncthreads();

  const int lane = threadIdx.x & 63;
  const int li = lane & 15;
  const int lh = lane >> 4;
  const int gw = (blockIdx.x * 256 + (int)threadIdx.x) >> 6;
  const int nw = (gridDim.x * 256) >> 6;

  short8v bfr[2][4];
#pragma unroll
  for (int s = 0; s < 2; ++s)
#pragma unroll
    for (int ct = 0; ct < 4; ++ct)
#pragma unroll
      for (int e = 0; e < 8; ++e)
        bfr[s][ct][e] = (short)Wbf2[(32 * s + 8 * lh + e) * HH + ct * 16 + li];

  short8v bhd[2];
#pragma unroll
  for (int s = 0; s < 2; ++s)
#pragma unroll
    for (int e = 0; e < 8; ++e)
      bhd[s][e] = (li < TT) ? f2bf(Wl0[(32 * s + 8 * lh + e) * TT + li]) : (short)0;

  const float4 sa0 = *(const float4*)(abl + 8 * lh);
  const float4 sa1 = *(const float4*)(abl + 8 * lh + 4);
  const float4 sb0 = *(const float4*)(abl + HH + 8 * lh);
  const float4 sb1 = *(const float4*)(abl + HH + 8 * lh + 4);
  const float4 ta0 = *(const float4*)(abl + 32 + 8 * lh);
  const float4 ta1 = *(const float4*)(abl + 32 + 8 * lh + 4);
  const float4 tb0 = *(const float4*)(abl + HH + 32 + 8 * lh);
  const float4 tb1 = *(const float4*)(abl + HH + 32 + 8 * lh + 4);
  const float blv = (li < TT) ? bl0[li] : 0.f;

  for (int t = gw; t < NN / 16; t += nw) {
    const ushort_t* hb = h1 + (size_t)(t * 16 + li) * HH + 8 * lh;
    uint4 xa = *(const uint4*)(hb);
    uint4 xc = *(const uint4*)(hb + 32);

    short8v af0, af1;
    af0[0] = f2bf(fmaxf(fmaf(sa0.x, bf2f(xa.x), sb0.x), 0.f));
    af0[1] = f2bf(fmaxf(fmaf(sa0.y, bfhi(xa.x), sb0.y), 0.f));
    af0[2] = f2bf(fmaxf(fmaf(sa0.z, bf2f(xa.y), sb0.z), 0.f));
    af0[3] = f2bf(fmaxf(fmaf(sa0.w, bfhi(xa.y), sb0.w), 0.f));
    af0[4] = f2bf(fmaxf(fmaf(sa1.x, bf2f(xa.z), sb1.x), 0.f));
    af0[5] = f2bf(fmaxf(fmaf(sa1.y, bfhi(xa.z), sb1.y), 0.f));
    af0[6] = f2bf(fmaxf(fmaf(sa1.z, bf2f(xa.w), sb1.z), 0.f));
    af0[7] = f2bf(fmaxf(fmaf(sa1.w, bfhi(xa.w), sb1.w), 0.f));
    af1[0] = f2bf(fmaxf(fmaf(ta0.x, bf2f(xc.x), tb0.x), 0.f));
    af1[1] = f2bf(fmaxf(fmaf(ta0.y, bfhi(xc.x), tb0.y), 0.f));
    af1[2] = f2bf(fmaxf(fmaf(ta0.z, bf2f(xc.y), tb0.z), 0.f));
    af1[3] = f2bf(fmaxf(fmaf(ta0.w, bfhi(xc.y), tb0.w), 0.f));
    af1[4] = f2bf(fmaxf(fmaf(ta1.x, bf2f(xc.z), tb1.x), 0.f));
    af1[5] = f2bf(fmaxf(fmaf(ta1.y, bfhi(xc.z), tb1.y), 0.f));
    af1[6] = f2bf(fmaxf(fmaf(ta1.z, bf2f(xc.w), tb1.z), 0.f));
    af1[7] = f2bf(fmaxf(fmaf(ta1.w, bfhi(xc.w), tb1.w), 0.f));

    f32x4 acc[4], acch;
#pragma unroll
    for (int ct = 0; ct < 4; ++ct) {
      acc[ct] = (f32x4){0.f, 0.f, 0.f, 0.f};
      acc[ct] = __builtin_amdgcn_mfma_f32_16x16x32_bf16(af0, bfr[0][ct], acc[ct], 0, 0, 0);
      acc[ct] = __builtin_amdgcn_mfma_f32_16x16x32_bf16(af1, bfr[1][ct], acc[ct], 0, 0, 0);
    }
    acch = (f32x4){0.f, 0.f, 0.f, 0.f};
    acch = __builtin_amdgcn_mfma_f32_16x16x32_bf16(af0, bhd[0], acch, 0, 0, 0);
    acch = __builtin_amdgcn_mfma_f32_16x16x32_bf16(af1, bhd[1], acch, 0, 0, 0);

    ushort_t* gb = g + (size_t)t * 16 * HH;
#pragma unroll
    for (int ct = 0; ct < 4; ++ct)
#pragma unroll
      for (int r = 0; r < 4; ++r)
        gb[(lh * 4 + r) * HH + ct * 16 + li] = (ushort_t)f2bf(acc[ct][r]);

    if (li < TT) {
#pragma unroll
      for (int r = 0; r < 4; ++r) {
        int row = t * 16 + lh * 4 + r;
        float np = acch[r] + blv;
        atomicMaxF(&lmax[batch[row] * TT + li], np);
        node_pred[(size_t)row * TT + li] = np;
      }
    }
  }
  __syncthreads();
  if (threadIdx.x < GG * TT) atomicMaxF(&maxbuf[threadIdx.x], lmax[threadIdx.x]);
}

// ---------------- fused: BN-finalize (in-block) + normalize+ReLU + head + max-pool ----
__global__ __launch_bounds__(256) void k_norm_np(
    const ushort_t* __restrict__ hin, const float* __restrict__ stats,
    const float* __restrict__ gamma, const float* __restrict__ beta,
    const float* __restrict__ Wlin, const float* __restrict__ blin,
    const int* __restrict__ batch, float* __restrict__ node_pred,
    float* __restrict__ maxbuf, int rpb) {
  __shared__ float lmax[GG * TT];
  __shared__ float abl[128];
  if (threadIdx.x < GG * TT) lmax[threadIdx.x] = -INFINITY;
  if (threadIdx.x < 64) {
    int c = threadIdx.x;
    float mu  = stats[c] * (1.f / NN);
    float var = stats[HH + c] * (1.f / NN) - mu * mu;
    float a = gamma[c] * rsqrtf(var + BN_EPS);
    abl[c] = a;
    abl[HH + c] = beta[c] - mu * a;
  }
  __syncthreads();

  const int lane = threadIdx.x & 63;
  const int wid  = threadIdx.x >> 6;
  const float a  = abl[lane];
  const float b2 = abl[HH + lane];
  const float4 w = ((const float4*)Wlin)[lane];
  const float4 bl = *(const float4*)blin;
  int r0 = blockIdx.x * rpb;
  int r1 = min(r0 + rpb, NN);

  for (int r = r0 + wid; r < r1; r += 4) {
    float h = bf2f(hin[(size_t)r * HH + lane]);
    float f = fmaxf(fmaf(a, h, b2), 0.f);
    float p0 = f * w.x, p1 = f * w.y, p2 = f * w.z, p3 = f * w.w;
#pragma unroll
    for (int off = 32; off; off >>= 1) {
      p0 += __shfl_xor(p0, off);
      p1 += __shfl_xor(p1, off);
      p2 += __shfl_xor(p2, off);
      p3 += __shfl_xor(p3, off);
    }
    if (lane == 0) {
      float4 np;
      np.x = p0 + bl.x; np.y = p1 + bl.y; np.z = p2 + bl.z; np.w = p3 + bl.w;
      int g = batch[r];
      atomicMaxF(&lmax[g * TT + 0], np.x);
      atomicMaxF(&lmax[g * TT + 1], np.y);
      atomicMaxF(&lmax[g * TT + 2], np.z);
      atomicMaxF(&lmax[g * TT + 3], np.w);
      float4* op = (float4*)(node_pred + (size_t)r * TT);
      float4 o = *op;
      np.x += o.x; np.y += o.y; np.z += o.z; np.w += o.w;
      *op = np;
    }
  }
  __syncthreads();
  if (threadIdx.x < GG * TT) atomicMaxF(&maxbuf[threadIdx.x], lmax[threadIdx.x]);
}

// ---------------- bucketed CSR build ----------------
__global__ __launch_bounds__(256) void k_part(
    const int* __restrict__ ei, int* __restrict__ Bcnt,
    uint2* __restrict__ ebuf) {
  __shared__ int hist[256], start[256], cnt[256], gbase[256];
  __shared__ int ssrc[PCHUNK], sdst[PCHUNK];
  const int t = threadIdx.x;
  hist[t] = 0; cnt[t] = 0;
  __syncthreads();
  const int e0 = blockIdx.x * PCHUNK;
  for (int i = t; i < PCHUNK; i += 256)
    atomicAdd(&hist[ei[NE + e0 + i] >> 9], 1);
  __syncthreads();
  int v = hist[t];
  start[t] = v;
  __syncthreads();
  for (int off = 1; off < 256; off <<= 1) {
    int u = (t >= off) ? start[t - off] : 0;
    __syncthreads();
    start[t] += u;
    __syncthreads();
  }
  int incl = start[t];
  __syncthreads();
  start[t] = incl - v;                       // exclusive
  if (v > 0) gbase[t] = atomicAdd(&Bcnt[t], v);
  __syncthreads();
  for (int i = t; i < PCHUNK; i += 256) {
    int src = ei[e0 + i];
    int dst = ei[NE + e0 + i];
    int b = dst >> 9;
    int p = start[b] + atomicAdd(&cnt[b], 1);
    ssrc[p] = src; sdst[p] = dst;
  }
  __syncthreads();
  for (int i = t; i < PCHUNK; i += 256) {
    int dst = sdst[i];
    int b = dst >> 9;
    uint2 pr; pr.x = (uint_t)ssrc[i]; pr.y = (uint_t)dst;
    ebuf[(size_t)b * BCAP + gbase[b] + (i - start[b])] = pr;
  }
}

__global__ void k_bscan(const int* __restrict__ Bcnt, int* __restrict__ Bbase) {
  __shared__ int s[256];
  int t = threadIdx.x;
  int v = 0;
  if (t < NBK) {
    int rows = min(BROWS, NN - t * BROWS);
    v = Bcnt[t] + rows;
  }
  s[t] = v;
  __syncthreads();
  for (int off = 1; off < 256; off <<= 1) {
    int u = (t >= off) ? s[t - off] : 0;
    __syncthreads();
    s[t] += u;
    __syncthreads();
  }
  if (t < NBK) Bbase[t] = s[t] - v;
}

__global__ __launch_bounds__(256) void k_fill2(
    const int* __restrict__ Bcnt, const int* __restrict__ Bbase,
    const uint2* __restrict__ ebuf, int* __restrict__ rowstart,
    int* __restrict__ srcl) {
  __shared__ int cnt[BROWS];
  __shared__ int ssum[256];
  const int b = blockIdx.x;
  const int r0 = b * BROWS;
  const int nrows = min(BROWS, NN - r0);
  const int ne = Bcnt[b];
  const int base = Bbase[b];
  const uint2* eb = ebuf + (size_t)b * BCAP;
  const int t = threadIdx.x;

  cnt[2 * t] = (2 * t < nrows) ? 1 : 0;
  cnt[2 * t + 1] = (2 * t + 1 < nrows) ? 1 : 0;
  __syncthreads();
  for (int j = t; j < ne; j += 256)
    atomicAdd(&cnt[(int)eb[j].y - r0], 1);
  __syncthreads();

  int a0 = cnt[2 * t], a1 = cnt[2 * t + 1];
  ssum[t] = a0 + a1;
  __syncthreads();
  for (int off = 1; off < 256; off <<= 1) {
    int u = (t >= off) ? ssum[t - off] : 0;
    __syncthreads();
    ssum[t] += u;
    __syncthreads();
  }
  int e0 = base + ssum[t] - (a0 + a1);
  int e1 = e0 + a0;
  __syncthreads();
  if (2 * t < nrows)     { rowstart[r0 + 2 * t] = e0;     srcl[e0] = r0 + 2 * t; }
  if (2 * t + 1 < nrows) { rowstart[r0 + 2 * t + 1] = e1; srcl[e1] = r0 + 2 * t + 1; }
  cnt[2 * t] = e0 + 1;
  cnt[2 * t + 1] = e1 + 1;
  __syncthreads();
  for (int j = t; j < ne; j += 256) {
    uint2 pr = eb[j];
    int p = atomicAdd(&cnt[(int)pr.y - r0], 1);
    srcl[p] = (int)pr.x;
  }
}

// ---------------- gather: h2[r] = b + sum_{srcl entries incl self} g[s] ----------------
#define RF(x) __builtin_amdgcn_readfirstlane(x)
#define GLD(V, I) asm volatile("global_load_ushort %0, %1, %2" \
    : "=v"(V) : "v"(voff), "s"(g + (size_t)(I) * HH) : "memory")
#define WAIT16 do { asm volatile("s_waitcnt vmcnt(16)" ::: "memory"); \
    __builtin_amdgcn_sched_barrier(0); } while (0)
#define WAIT0 do { asm volatile("s_waitcnt vmcnt(0)" ::: "memory"); \
    __builtin_amdgcn_sched_barrier(0); } while (0)
#define ISSUE16(P, EB) do { \
  int j0 = RF(srcl[(EB) + 0]),  j1 = RF(srcl[(EB) + 1]); \
  int j2 = RF(srcl[(EB) + 2]),  j3 = RF(srcl[(EB) + 3]); \
  int j4 = RF(srcl[(EB) + 4]),  j5 = RF(srcl[(EB) + 5]); \
  int j6 = RF(srcl[(EB) + 6]),  j7 = RF(srcl[(EB) + 7]); \
  int j8 = RF(srcl[(EB) + 8]),  j9 = RF(srcl[(EB) + 9]); \
  int j10 = RF(srcl[(EB) + 10]), j11 = RF(srcl[(EB) + 11]); \
  int j12 = RF(srcl[(EB) + 12]), j13 = RF(srcl[(EB) + 13]); \
  int j14 = RF(srcl[(EB) + 14]), j15 = RF(srcl[(EB) + 15]); \
  GLD(P##0, j0);  GLD(P##1, j1);  GLD(P##2, j2);  GLD(P##3, j3); \
  GLD(P##4, j4);  GLD(P##5, j5);  GLD(P##6, j6);  GLD(P##7, j7); \
  GLD(P##8, j8);  GLD(P##9, j9);  GLD(P##10, j10); GLD(P##11, j11); \
  GLD(P##12, j12); GLD(P##13, j13); GLD(P##14, j14); GLD(P##15, j15); \
} while (0)
#define CJ(V, EI) do { \
  if ((EI) == nb) { \
    h2[(size_t)cur * HH + lane] = (ushort_t)f2bf(acc); ps += acc; pss += acc * acc; \
    cur++; nb = __builtin_amdgcn_readlane(rsv, cur - wra); acc = bc; \
  } \
  acc += bf2f(V); } while (0)
#define CONS16(P, EB) do { \
  CJ(P##0, (EB) + 0);  CJ(P##1, (EB) + 1);  CJ(P##2, (EB) + 2);  CJ(P##3, (EB) + 3); \
  CJ(P##4, (EB) + 4);  CJ(P##5, (EB) + 5);  CJ(P##6, (EB) + 6);  CJ(P##7, (EB) + 7); \
  CJ(P##8, (EB) + 8);  CJ(P##9, (EB) + 9);  CJ(P##10, (EB) + 10); CJ(P##11, (EB) + 11); \
  CJ(P##12, (EB) + 12); CJ(P##13, (EB) + 13); CJ(P##14, (EB) + 14); CJ(P##15, (EB) + 15); \
} while (0)

__global__ __launch_bounds__(256) void k_gather(
    const ushort_t* __restrict__ g, const int* __restrict__ rowstart,
    const int* __restrict__ srcl, const float* __restrict__ bias,
    ushort_t* __restrict__ h2, float* __restrict__ stats) {
  const int lane = threadIdx.x & 63;
  const int wid  = threadIdx.x >> 6;
  const float bc = bias[lane];
  const uint_t voff = lane * 2;
  const int wra = (blockIdx.x * 4 + wid) * 8;

  int ridx = wra + 1 + lane;
  int rsv = (ridx < NN) ? rowstart[ridx] : NTOT;

  int e    = RF(rowstart[wra]);
  int eEnd = __builtin_amdgcn_readlane(rsv, 7);
  int cur  = wra;
  int nb   = __builtin_amdgcn_readlane(rsv, 0);
  float acc = bc, ps = 0.f, pss = 0.f;

  uint_t A0, A1, A2, A3, A4, A5, A6, A7, A8, A9, A10, A11, A12, A13, A14, A15;
  uint_t B0, B1, B2, B3, B4, B5, B6, B7, B8, B9, B10, B11, B12, B13, B14, B15;

  int n = (eEnd - e) >> 4;
  if (n > 0) {
    int pend = e;
    ISSUE16(A, e); e += 16; n--;
    while (n >= 2) {
      int eb = e;
      ISSUE16(B, e); e += 16; n--;
      WAIT16; CONS16(A, pend); pend = eb;
      int ea = e;
      ISSUE16(A, e); e += 16; n--;
      WAIT16; CONS16(B, pend); pend = ea;
    }
    if (n == 1) {
      int eb = e;
      ISSUE16(B, e); e += 16;
      WAIT16; CONS16(A, pend); pend = eb;
      WAIT0;  CONS16(B, pend);
    } else {
      WAIT0;  CONS16(A, pend);
    }
  }
  for (; e < eEnd; ++e) {
    if (e == nb) {
      h2[(size_t)cur * HH + lane] = (ushort_t)f2bf(acc); ps += acc; pss += acc * acc;
      cur++; nb = __builtin_amdgcn_readlane(rsv, cur - wra); acc = bc;
    }
    int i = RF(srcl[e]);
    acc += bf2f(g[(size_t)i * HH + lane]);
  }
  h2[(size_t)cur * HH + lane] = (ushort_t)f2bf(acc); ps += acc; pss += acc * acc;

  __shared__ float sred[4][128];
  sred[wid][lane] = ps;
  sred[wid][64 + lane] = pss;
  __syncthreads();
  if (wid == 0) {
    float s0 = sred[0][lane] + sred[1][lane] + sred[2][lane] + sred[3][lane];
    float q0 = sred[0][64 + lane] + sred[1][64 + lane] + sred[2][64 + lane] + sred[3][64 + lane];
    atomicAdd(&stats[lane], s0);
    atomicAdd(&stats[HH + lane], q0);
  }
}

// ---------------- final: wsi = max0 + max1 ----------------
__global__ void k_wsi(const float* __restrict__ m0, const float* __restrict__ m1,
                      float* __restrict__ out) {
  int i = threadIdx.x;
  out[i] = m0[i] + m1[i];
}

extern "C" void kernel_launch(void* const* d_in, const int* in_sizes, int n_in,
                              void* d_out, int out_size, void* d_ws, size_t ws_size,
                              hipStream_t stream) {
  const float* x    = (const float*)d_in[0];
  const int*   ei   = (const int*)d_in[1];
  const int*   bat  = (const int*)d_in[2];
  const float* Wf   = (const float*)d_in[3];
  const float* bf   = (const float*)d_in[4];
  const float* g1   = (const float*)d_in[5];
  const float* be1  = (const float*)d_in[6];
  const float* Wl0  = (const float*)d_in[7];
  const float* bl0  = (const float*)d_in[8];
  const float* Wc   = (const float*)d_in[9];
  const float* bc   = (const float*)d_in[10];
  const float* g2   = (const float*)d_in[11];
  const float* be2  = (const float*)d_in[12];
  const float* Wl1  = (const float*)d_in[13];
  const float* bl1  = (const float*)d_in[14];

  float* out   = (float*)d_out;
  float* wsi   = out;                 // [8,4]
  float* npred = out + GG * TT;       // [N,4]

  ushort_t* h2bf   = (ushort_t*)d_ws;                 // N*H bf16 (h2)
  ushort_t* h1bf   = h2bf + (size_t)NN * HH;          // N*H bf16 (h1)
  ushort_t* gbf    = h1bf + (size_t)NN * HH;          // N*H bf16 (g)
  float*    stats1 = (float*)(gbf + (size_t)NN * HH); // 256
  float*    stats2 = stats1 + 256;                    // 256
  float*    maxb   = stats2 + 256;                    // 64
  int*      rowstart = (int*)(maxb + 64);             // N
  int*      Bcnt     = rowstart + NN;                 // 256
  int*      Bbase    = Bcnt + 256;                    // 256
  int*      srcl     = Bbase + 256;                   // NE+NN (self-loops)
  uint2*    ebuf     = (uint2*)(srcl + NTOT);         // NBK*BCAP pairs (16 MB)
  ushort_t* Wbf      = (ushort_t*)(ebuf + (size_t)NBK * BCAP);  // DF*HH
  ushort_t* Wbf2     = Wbf + DF * HH;                 // HH*HH

  // setup + bucketed CSR build
  k_setup<<<dim3(80), dim3(256), 0, stream>>>(Wf, Wbf, Wc, Wbf2, stats1, maxb, Bcnt);
  k_part<<<dim3(NPB), dim3(256), 0, stream>>>(ei, Bcnt, ebuf);
  k_bscan<<<dim3(1), dim3(256), 0, stream>>>(Bcnt, Bbase);
  k_fill2<<<dim3(NBK), dim3(256), 0, stream>>>(Bcnt, Bbase, ebuf, rowstart, srcl);

  // Layer 0: GEMM + stats (W in registers — R14 proven config)
  k_gemm1_mfma<<<dim3(512), dim3(256), 0, stream>>>(x, Wbf, bf, h1bf, stats1);
  k_norm_gemm2<<<dim3(512), dim3(256), 0, stream>>>(
      h1bf, stats1, g1, be1, Wl0, bl0, bat, Wbf2, npred, maxb, gbf);

  // Layer 1: h2 = b + g + A.g (2-deep pipelined flat-stream gather)
  k_gather<<<dim3(NN / 32), dim3(256), 0, stream>>>(
      gbf, rowstart, srcl, bc, h2bf, stats2);
  k_norm_np<<<dim3(512), dim3(256), 0, stream>>>(
      h2bf, stats2, g2, be2, Wl1, bl1, bat, npred, maxb + 32, (NN + 511) / 512);

  k_wsi<<<dim3(1), dim3(32), 0, stream>>>(maxb, maxb + 32, wsi);
}

// Round 17
// 293.732 us; speedup vs baseline: 1.1726x; 1.0049x over previous
//
#include <hip/hip_runtime.h>
#include <math.h>

#define NN 100000
#define NE 1600000
#define DF 256
#define HH 64
#define TT 4
#define GG 8
#define BN_EPS 1e-5f
#define NTOT (NE + NN)               // srcl entries incl. self-loops

#define BROWS 512                    // rows per bucket
#define NBK ((NN + BROWS - 1) / BROWS)   // 196
#define BCAP 10240                   // bucket capacity (mean 8192, sigma 90)
#define PCHUNK 1600
#define NPB (NE / PCHUNK)            // 1000

typedef __attribute__((ext_vector_type(8))) short short8v;
typedef __attribute__((ext_vector_type(4))) float f32x4;
typedef unsigned short ushort_t;
typedef unsigned char uchar_t;
typedef unsigned int uint_t;

__device__ __forceinline__ void atomicMaxF(float* addr, float val) {
  if (val >= 0.f) atomicMax((int*)addr, __float_as_int(val));
  else            atomicMin((unsigned int*)addr, __float_as_uint(val));
}

__device__ __forceinline__ short f2bf(float f) {
  uint_t u = __float_as_uint(f);
  u += 0x7FFFu + ((u >> 16) & 1u);
  return (short)(u >> 16);
}
__device__ __forceinline__ float bf2f(uint_t u) { return __uint_as_float(u << 16); }
__device__ __forceinline__ float bfhi(uint_t u) { return __uint_as_float(u & 0xFFFF0000u); }
// fp8 e4m3 (OCP on gfx950) HW convert
__device__ __forceinline__ uint_t pk8(float a, float b) {
  return (uint_t)__builtin_amdgcn_cvt_pk_fp8_f32(a, b, 0, false);
}
__device__ __forceinline__ float fp8f(uint_t v) {
  return __builtin_amdgcn_cvt_f32_fp8(v, 0);
}

// ---------------- setup: W->bf16, stats=0, maxb=-inf, Bcnt=0 ----------------
__global__ void k_setup(const float* __restrict__ Wf, ushort_t* __restrict__ Wbf,
                        const float* __restrict__ Wc, ushort_t* __restrict__ Wbf2,
                        float* __restrict__ stats, float* __restrict__ maxb,
                        int* __restrict__ Bcnt) {
  int i = blockIdx.x * 256 + threadIdx.x;       // 80 blocks x 256 = 20480
  if (i < DF * HH) Wbf[i] = (ushort_t)f2bf(Wf[i]);
  else {
    int j = i - DF * HH;
    if (j < HH * HH) Wbf2[j] = (ushort_t)f2bf(Wc[j]);
  }
  if (i < 512) stats[i] = 0.f;
  if (i < 64)  maxb[i]  = -INFINITY;
  if (i < NBK) Bcnt[i]  = 0;
}

// ---------------- GEMM1 (MFMA bf16): h1 = x @ W_first + b (bf16 out), + BN stats ----
// W in REGISTERS (R14 proven config).
__global__ __launch_bounds__(256, 2) void k_gemm1_mfma(
    const float* __restrict__ x, const ushort_t* __restrict__ Wbf,
    const float* __restrict__ b, ushort_t* __restrict__ h1,
    float* __restrict__ stats) {
  const int lane = threadIdx.x & 63;
  const int li = lane & 15;
  const int lh = lane >> 4;
  const int gw = (blockIdx.x * 256 + (int)threadIdx.x) >> 6;
  const int nw = (gridDim.x * 256) >> 6;

  short8v bf[8][4];
#pragma unroll
  for (int s = 0; s < 8; ++s)
#pragma unroll
    for (int ct = 0; ct < 4; ++ct)
#pragma unroll
      for (int e = 0; e < 8; ++e)
        bf[s][ct][e] = (short)Wbf[(32 * s + 8 * lh + e) * HH + ct * 16 + li];

  float bias[4];
#pragma unroll
  for (int ct = 0; ct < 4; ++ct) bias[ct] = b[ct * 16 + li];

  float ps[4] = {0.f, 0.f, 0.f, 0.f}, pss[4] = {0.f, 0.f, 0.f, 0.f};

  for (int t = gw; t < NN / 16; t += nw) {
    const float* xb = x + (size_t)(t * 16 + li) * DF + 8 * lh;
    f32x4 acc[4];
#pragma unroll
    for (int ct = 0; ct < 4; ++ct) acc[ct] = (f32x4){0.f, 0.f, 0.f, 0.f};

#pragma unroll
    for (int s = 0; s < 8; ++s) {
      float4 a0 = *(const float4*)(xb + 32 * s);
      float4 a1 = *(const float4*)(xb + 32 * s + 4);
      short8v af;
      af[0] = f2bf(a0.x); af[1] = f2bf(a0.y); af[2] = f2bf(a0.z); af[3] = f2bf(a0.w);
      af[4] = f2bf(a1.x); af[5] = f2bf(a1.y); af[6] = f2bf(a1.z); af[7] = f2bf(a1.w);
#pragma unroll
      for (int ct = 0; ct < 4; ++ct)
        acc[ct] = __builtin_amdgcn_mfma_f32_16x16x32_bf16(af, bf[s][ct], acc[ct], 0, 0, 0);
    }

    ushort_t* hb = h1 + (size_t)t * 16 * HH;
#pragma unroll
    for (int ct = 0; ct < 4; ++ct) {
#pragma unroll
      for (int r = 0; r < 4; ++r) {
        float h = acc[ct][r] + bias[ct];
        hb[(lh * 4 + r) * HH + ct * 16 + li] = (ushort_t)f2bf(h);
        ps[ct] += h; pss[ct] += h * h;
      }
    }
  }

#pragma unroll
  for (int ct = 0; ct < 4; ++ct) {
    ps[ct]  += __shfl_xor(ps[ct], 16);  ps[ct]  += __shfl_xor(ps[ct], 32);
    pss[ct] += __shfl_xor(pss[ct], 16); pss[ct] += __shfl_xor(pss[ct], 32);
  }
  if (lane < 16) {
#pragma unroll
    for (int ct = 0; ct < 4; ++ct) {
      atomicAdd(&stats[ct * 16 + lane], ps[ct]);
      atomicAdd(&stats[HH + ct * 16 + lane], pss[ct]);
    }
  }
}

// ---------------- fused: BN-finalize (in-block) + normalize(h1)+ReLU;
//                  np0 + pool via 5th MFMA tile; g = f @ W_conv (fp8 out) ----------------
__global__ __launch_bounds__(256) void k_norm_gemm2(
    const ushort_t* __restrict__ h1, const float* __restrict__ stats,
    const float* __restrict__ gamma, const float* __restrict__ beta,
    const float* __restrict__ Wl0, const float* __restrict__ bl0,
    const int* __restrict__ batch, const ushort_t* __restrict__ Wbf2,
    float* __restrict__ node_pred, float* __restrict__ maxbuf,
    uchar_t* __restrict__ g) {
  __shared__ float lmax[GG * TT];
  __shared__ float abl[128];
  if (threadIdx.x < GG * TT) lmax[threadIdx.x] = -INFINITY;
  if (threadIdx.x < 64) {
    int c = threadIdx.x;
    float mu  = stats[c] * (1.f / NN);
    float var = stats[HH + c] * (1.f / NN) - mu * mu;
    float a = gamma[c] * rsqrtf(var + BN_EPS);
    abl[c] = a;
    abl[HH + c] = beta[c] - mu * a;
  }
  __syncthreads();

  const int lane = threadIdx.x & 63;
  const int li = lane & 15;
  const int lh = lane >> 4;
  const int gw = (blockIdx.x * 256 + (int)threadIdx.x) >> 6;
  const int nw = (gridDim.x * 256) >> 6;

  short8v bfr[2][4];
#pragma unroll
  for (int s = 0; s < 2; ++s)
#pragma unroll
    for (int ct = 0; ct < 4; ++ct)
#pragma unroll
      for (int e = 0; e < 8; ++e)
        bfr[s][ct][e] = (short)Wbf2[(32 * s + 8 * lh + e) * HH + ct * 16 + li];

  short8v bhd[2];
#pragma unroll
  for (int s = 0; s < 2; ++s)
#pragma unroll
    for (int e = 0; e < 8; ++e)
      bhd[s][e] = (li < TT) ? f2bf(Wl0[(32 * s + 8 * lh + e) * TT + li]) : (short)0;

  const float4 sa0 = *(const float4*)(abl + 8 * lh);
  const float4 sa1 = *(const float4*)(abl + 8 * lh + 4);
  const float4 sb0 = *(const float4*)(abl + HH + 8 * lh);
  const float4 sb1 = *(const float4*)(abl + HH + 8 * lh + 4);
  const float4 ta0 = *(const float4*)(abl + 32 + 8 * lh);
  const float4 ta1 = *(const float4*)(abl + 32 + 8 * lh + 4);
  const float4 tb0 = *(const float4*)(abl + HH + 32 + 8 * lh);
  const float4 tb1 = *(const float4*)(abl + HH + 32 + 8 * lh + 4);
  const float blv = (li < TT) ? bl0[li] : 0.f;

  for (int t = gw; t < NN / 16; t += nw) {
    const ushort_t* hb = h1 + (size_t)(t * 16 + li) * HH + 8 * lh;
    uint4 xa = *(const uint4*)(hb);
    uint4 xc = *(const uint4*)(hb + 32);

    short8v af0, af1;
    af0[0] = f2bf(fmaxf(fmaf(sa0.x, bf2f(xa.x), sb0.x), 0.f));
    af0[1] = f2bf(fmaxf(fmaf(sa0.y, bfhi(xa.x), sb0.y), 0.f));
    af0[2] = f2bf(fmaxf(fmaf(sa0.z, bf2f(xa.y), sb0.z), 0.f));
    af0[3] = f2bf(fmaxf(fmaf(sa0.w, bfhi(xa.y), sb0.w), 0.f));
    af0[4] = f2bf(fmaxf(fmaf(sa1.x, bf2f(xa.z), sb1.x), 0.f));
    af0[5] = f2bf(fmaxf(fmaf(sa1.y, bfhi(xa.z), sb1.y), 0.f));
    af0[6] = f2bf(fmaxf(fmaf(sa1.z, bf2f(xa.w), sb1.z), 0.f));
    af0[7] = f2bf(fmaxf(fmaf(sa1.w, bfhi(xa.w), sb1.w), 0.f));
    af1[0] = f2bf(fmaxf(fmaf(ta0.x, bf2f(xc.x), tb0.x), 0.f));
    af1[1] = f2bf(fmaxf(fmaf(ta0.y, bfhi(xc.x), tb0.y), 0.f));
    af1[2] = f2bf(fmaxf(fmaf(ta0.z, bf2f(xc.y), tb0.z), 0.f));
    af1[3] = f2bf(fmaxf(fmaf(ta0.w, bfhi(xc.y), tb0.w), 0.f));
    af1[4] = f2bf(fmaxf(fmaf(ta1.x, bf2f(xc.z), tb1.x), 0.f));
    af1[5] = f2bf(fmaxf(fmaf(ta1.y, bfhi(xc.z), tb1.y), 0.f));
    af1[6] = f2bf(fmaxf(fmaf(ta1.z, bf2f(xc.w), tb1.z), 0.f));
    af1[7] = f2bf(fmaxf(fmaf(ta1.w, bfhi(xc.w), tb1.w), 0.f));

    f32x4 acc[4], acch;
#pragma unroll
    for (int ct = 0; ct < 4; ++ct) {
      acc[ct] = (f32x4){0.f, 0.f, 0.f, 0.f};
      acc[ct] = __builtin_amdgcn_mfma_f32_16x16x32_bf16(af0, bfr[0][ct], acc[ct], 0, 0, 0);
      acc[ct] = __builtin_amdgcn_mfma_f32_16x16x32_bf16(af1, bfr[1][ct], acc[ct], 0, 0, 0);
    }
    acch = (f32x4){0.f, 0.f, 0.f, 0.f};
    acch = __builtin_amdgcn_mfma_f32_16x16x32_bf16(af0, bhd[0], acch, 0, 0, 0);
    acch = __builtin_amdgcn_mfma_f32_16x16x32_bf16(af1, bhd[1], acch, 0, 0, 0);

    uchar_t* gb = g + (size_t)t * 16 * HH;
#pragma unroll
    for (int ct = 0; ct < 4; ++ct) {
#pragma unroll
      for (int r = 0; r < 4; r += 2) {
        uint_t p = pk8(acc[ct][r], acc[ct][r + 1]);
        gb[(lh * 4 + r) * HH + ct * 16 + li]     = (uchar_t)(p & 0xFF);
        gb[(lh * 4 + r + 1) * HH + ct * 16 + li] = (uchar_t)((p >> 8) & 0xFF);
      }
    }

    if (li < TT) {
#pragma unroll
      for (int r = 0; r < 4; ++r) {
        int row = t * 16 + lh * 4 + r;
        float np = acch[r] + blv;
        atomicMaxF(&lmax[batch[row] * TT + li], np);
        node_pred[(size_t)row * TT + li] = np;
      }
    }
  }
  __syncthreads();
  if (threadIdx.x < GG * TT) atomicMaxF(&maxbuf[threadIdx.x], lmax[threadIdx.x]);
}

// ---------------- fused: BN-finalize (in-block) + normalize+ReLU + head + max-pool ----
__global__ __launch_bounds__(256) void k_norm_np(
    const ushort_t* __restrict__ hin, const float* __restrict__ stats,
    const float* __restrict__ gamma, const float* __restrict__ beta,
    const float* __restrict__ Wlin, const float* __restrict__ blin,
    const int* __restrict__ batch, float* __restrict__ node_pred,
    float* __restrict__ maxbuf, int rpb) {
  __shared__ float lmax[GG * TT];
  __shared__ float abl[128];
  if (threadIdx.x < GG * TT) lmax[threadIdx.x] = -INFINITY;
  if (threadIdx.x < 64) {
    int c = threadIdx.x;
    float mu  = stats[c] * (1.f / NN);
    float var = stats[HH + c] * (1.f / NN) - mu * mu;
    float a = gamma[c] * rsqrtf(var + BN_EPS);
    abl[c] = a;
    abl[HH + c] = beta[c] - mu * a;
  }
  __syncthreads();

  const int lane = threadIdx.x & 63;
  const int wid  = threadIdx.x >> 6;
  const float a  = abl[lane];
  const float b2 = abl[HH + lane];
  const float4 w = ((const float4*)Wlin)[lane];
  const float4 bl = *(const float4*)blin;
  int r0 = blockIdx.x * rpb;
  int r1 = min(r0 + rpb, NN);

  for (int r = r0 + wid; r < r1; r += 4) {
    float h = bf2f(hin[(size_t)r * HH + lane]);
    float f = fmaxf(fmaf(a, h, b2), 0.f);
    float p0 = f * w.x, p1 = f * w.y, p2 = f * w.z, p3 = f * w.w;
#pragma unroll
    for (int off = 32; off; off >>= 1) {
      p0 += __shfl_xor(p0, off);
      p1 += __shfl_xor(p1, off);
      p2 += __shfl_xor(p2, off);
      p3 += __shfl_xor(p3, off);
    }
    if (lane == 0) {
      float4 np;
      np.x = p0 + bl.x; np.y = p1 + bl.y; np.z = p2 + bl.z; np.w = p3 + bl.w;
      int g = batch[r];
      atomicMaxF(&lmax[g * TT + 0], np.x);
      atomicMaxF(&lmax[g * TT + 1], np.y);
      atomicMaxF(&lmax[g * TT + 2], np.z);
      atomicMaxF(&lmax[g * TT + 3], np.w);
      float4* op = (float4*)(node_pred + (size_t)r * TT);
      float4 o = *op;
      np.x += o.x; np.y += o.y; np.z += o.z; np.w += o.w;
      *op = np;
    }
  }
  __syncthreads();
  if (threadIdx.x < GG * TT) atomicMaxF(&maxbuf[threadIdx.x], lmax[threadIdx.x]);
}

// ---------------- bucketed CSR build ----------------
__global__ __launch_bounds__(256) void k_part(
    const int* __restrict__ ei, int* __restrict__ Bcnt,
    uint2* __restrict__ ebuf) {
  __shared__ int hist[256], start[256], cnt[256], gbase[256];
  __shared__ int ssrc[PCHUNK], sdst[PCHUNK];
  const int t = threadIdx.x;
  hist[t] = 0; cnt[t] = 0;
  __syncthreads();
  const int e0 = blockIdx.x * PCHUNK;
  for (int i = t; i < PCHUNK; i += 256)
    atomicAdd(&hist[ei[NE + e0 + i] >> 9], 1);
  __syncthreads();
  int v = hist[t];
  start[t] = v;
  __syncthreads();
  for (int off = 1; off < 256; off <<= 1) {
    int u = (t >= off) ? start[t - off] : 0;
    __syncthreads();
    start[t] += u;
    __syncthreads();
  }
  int incl = start[t];
  __syncthreads();
  start[t] = incl - v;                       // exclusive
  if (v > 0) gbase[t] = atomicAdd(&Bcnt[t], v);
  __syncthreads();
  for (int i = t; i < PCHUNK; i += 256) {
    int src = ei[e0 + i];
    int dst = ei[NE + e0 + i];
    int b = dst >> 9;
    int p = start[b] + atomicAdd(&cnt[b], 1);
    ssrc[p] = src; sdst[p] = dst;
  }
  __syncthreads();
  for (int i = t; i < PCHUNK; i += 256) {
    int dst = sdst[i];
    int b = dst >> 9;
    uint2 pr; pr.x = (uint_t)ssrc[i]; pr.y = (uint_t)dst;
    ebuf[(size_t)b * BCAP + gbase[b] + (i - start[b])] = pr;
  }
}

__global__ void k_bscan(const int* __restrict__ Bcnt, int* __restrict__ Bbase) {
  __shared__ int s[256];
  int t = threadIdx.x;
  int v = 0;
  if (t < NBK) {
    int rows = min(BROWS, NN - t * BROWS);
    v = Bcnt[t] + rows;
  }
  s[t] = v;
  __syncthreads();
  for (int off = 1; off < 256; off <<= 1) {
    int u = (t >= off) ? s[t - off] : 0;
    __syncthreads();
    s[t] += u;
    __syncthreads();
  }
  if (t < NBK) Bbase[t] = s[t] - v;
}

__global__ __launch_bounds__(256) void k_fill2(
    const int* __restrict__ Bcnt, const int* __restrict__ Bbase,
    const uint2* __restrict__ ebuf, int* __restrict__ rowstart,
    int* __restrict__ srcl) {
  __shared__ int cnt[BROWS];
  __shared__ int ssum[256];
  const int b = blockIdx.x;
  const int r0 = b * BROWS;
  const int nrows = min(BROWS, NN - r0);
  const int ne = Bcnt[b];
  const int base = Bbase[b];
  const uint2* eb = ebuf + (size_t)b * BCAP;
  const int t = threadIdx.x;

  cnt[2 * t] = (2 * t < nrows) ? 1 : 0;
  cnt[2 * t + 1] = (2 * t + 1 < nrows) ? 1 : 0;
  __syncthreads();
  for (int j = t; j < ne; j += 256)
    atomicAdd(&cnt[(int)eb[j].y - r0], 1);
  __syncthreads();

  int a0 = cnt[2 * t], a1 = cnt[2 * t + 1];
  ssum[t] = a0 + a1;
  __syncthreads();
  for (int off = 1; off < 256; off <<= 1) {
    int u = (t >= off) ? ssum[t - off] : 0;
    __syncthreads();
    ssum[t] += u;
    __syncthreads();
  }
  int e0 = base + ssum[t] - (a0 + a1);
  int e1 = e0 + a0;
  __syncthreads();
  if (2 * t < nrows)     { rowstart[r0 + 2 * t] = e0;     srcl[e0] = r0 + 2 * t; }
  if (2 * t + 1 < nrows) { rowstart[r0 + 2 * t + 1] = e1; srcl[e1] = r0 + 2 * t + 1; }
  cnt[2 * t] = e0 + 1;
  cnt[2 * t + 1] = e1 + 1;
  __syncthreads();
  for (int j = t; j < ne; j += 256) {
    uint2 pr = eb[j];
    int p = atomicAdd(&cnt[(int)pr.y - r0], 1);
    srcl[p] = (int)pr.x;
  }
}

// ---------------- gather: h2[r] = b + sum_{srcl entries incl self} g[s] ----------------
// fp8 g rows (64 B = ONE cache line per edge). 2-deep ping-pong (proven config).
#define RF(x) __builtin_amdgcn_readfirstlane(x)
#define GLD(V, I) asm volatile("global_load_ubyte %0, %1, %2" \
    : "=v"(V) : "v"(voff), "s"(g + (size_t)(I) * HH) : "memory")
#define WAIT16 do { asm volatile("s_waitcnt vmcnt(16)" ::: "memory"); \
    __builtin_amdgcn_sched_barrier(0); } while (0)
#define WAIT0 do { asm volatile("s_waitcnt vmcnt(0)" ::: "memory"); \
    __builtin_amdgcn_sched_barrier(0); } while (0)
#define ISSUE16(P, EB) do { \
  int j0 = RF(srcl[(EB) + 0]),  j1 = RF(srcl[(EB) + 1]); \
  int j2 = RF(srcl[(EB) + 2]),  j3 = RF(srcl[(EB) + 3]); \
  int j4 = RF(srcl[(EB) + 4]),  j5 = RF(srcl[(EB) + 5]); \
  int j6 = RF(srcl[(EB) + 6]),  j7 = RF(srcl[(EB) + 7]); \
  int j8 = RF(srcl[(EB) + 8]),  j9 = RF(srcl[(EB) + 9]); \
  int j10 = RF(srcl[(EB) + 10]), j11 = RF(srcl[(EB) + 11]); \
  int j12 = RF(srcl[(EB) + 12]), j13 = RF(srcl[(EB) + 13]); \
  int j14 = RF(srcl[(EB) + 14]), j15 = RF(srcl[(EB) + 15]); \
  GLD(P##0, j0);  GLD(P##1, j1);  GLD(P##2, j2);  GLD(P##3, j3); \
  GLD(P##4, j4);  GLD(P##5, j5);  GLD(P##6, j6);  GLD(P##7, j7); \
  GLD(P##8, j8);  GLD(P##9, j9);  GLD(P##10, j10); GLD(P##11, j11); \
  GLD(P##12, j12); GLD(P##13, j13); GLD(P##14, j14); GLD(P##15, j15); \
} while (0)
#define CJ(V, EI) do { \
  if ((EI) == nb) { \
    h2[(size_t)cur * HH + lane] = (ushort_t)f2bf(acc); ps += acc; pss += acc * acc; \
    cur++; nb = __builtin_amdgcn_readlane(rsv, cur - wra); acc = bc; \
  } \
  acc += fp8f(V); } while (0)
#define CONS16(P, EB) do { \
  CJ(P##0, (EB) + 0);  CJ(P##1, (EB) + 1);  CJ(P##2, (EB) + 2);  CJ(P##3, (EB) + 3); \
  CJ(P##4, (EB) + 4);  CJ(P##5, (EB) + 5);  CJ(P##6, (EB) + 6);  CJ(P##7, (EB) + 7); \
  CJ(P##8, (EB) + 8);  CJ(P##9, (EB) + 9);  CJ(P##10, (EB) + 10); CJ(P##11, (EB) + 11); \
  CJ(P##12, (EB) + 12); CJ(P##13, (EB) + 13); CJ(P##14, (EB) + 14); CJ(P##15, (EB) + 15); \
} while (0)

__global__ __launch_bounds__(256) void k_gather(
    const uchar_t* __restrict__ g, const int* __restrict__ rowstart,
    const int* __restrict__ srcl, const float* __restrict__ bias,
    ushort_t* __restrict__ h2, float* __restrict__ stats) {
  const int lane = threadIdx.x & 63;
  const int wid  = threadIdx.x >> 6;
  const float bc = bias[lane];
  const uint_t voff = lane;            // 1 byte per lane
  const int wra = (blockIdx.x * 4 + wid) * 8;

  int ridx = wra + 1 + lane;
  int rsv = (ridx < NN) ? rowstart[ridx] : NTOT;

  int e    = RF(rowstart[wra]);
  int eEnd = __builtin_amdgcn_readlane(rsv, 7);
  int cur  = wra;
  int nb   = __builtin_amdgcn_readlane(rsv, 0);
  float acc = bc, ps = 0.f, pss = 0.f;

  uint_t A0, A1, A2, A3, A4, A5, A6, A7, A8, A9, A10, A11, A12, A13, A14, A15;
  uint_t B0, B1, B2, B3, B4, B5, B6, B7, B8, B9, B10, B11, B12, B13, B14, B15;

  int n = (eEnd - e) >> 4;
  if (n > 0) {
    int pend = e;
    ISSUE16(A, e); e += 16; n--;
    while (n >= 2) {
      int eb = e;
      ISSUE16(B, e); e += 16; n--;
      WAIT16; CONS16(A, pend); pend = eb;
      int ea = e;
      ISSUE16(A, e); e += 16; n--;
      WAIT16; CONS16(B, pend); pend = ea;
    }
    if (n == 1) {
      int eb = e;
      ISSUE16(B, e); e += 16;
      WAIT16; CONS16(A, pend); pend = eb;
      WAIT0;  CONS16(B, pend);
    } else {
      WAIT0;  CONS16(A, pend);
    }
  }
  for (; e < eEnd; ++e) {
    if (e == nb) {
      h2[(size_t)cur * HH + lane] = (ushort_t)f2bf(acc); ps += acc; pss += acc * acc;
      cur++; nb = __builtin_amdgcn_readlane(rsv, cur - wra); acc = bc;
    }
    int i = RF(srcl[e]);
    acc += fp8f(g[(size_t)i * HH + lane]);
  }
  h2[(size_t)cur * HH + lane] = (ushort_t)f2bf(acc); ps += acc; pss += acc * acc;

  __shared__ float sred[4][128];
  sred[wid][lane] = ps;
  sred[wid][64 + lane] = pss;
  __syncthreads();
  if (wid == 0) {
    float s0 = sred[0][lane] + sred[1][lane] + sred[2][lane] + sred[3][lane];
    float q0 = sred[0][64 + lane] + sred[1][64 + lane] + sred[2][64 + lane] + sred[3][64 + lane];
    atomicAdd(&stats[lane], s0);
    atomicAdd(&stats[HH + lane], q0);
  }
}

// ---------------- final: wsi = max0 + max1 ----------------
__global__ void k_wsi(const float* __restrict__ m0, const float* __restrict__ m1,
                      float* __restrict__ out) {
  int i = threadIdx.x;
  out[i] = m0[i] + m1[i];
}

extern "C" void kernel_launch(void* const* d_in, const int* in_sizes, int n_in,
                              void* d_out, int out_size, void* d_ws, size_t ws_size,
                              hipStream_t stream) {
  const float* x    = (const float*)d_in[0];
  const int*   ei   = (const int*)d_in[1];
  const int*   bat  = (const int*)d_in[2];
  const float* Wf   = (const float*)d_in[3];
  const float* bf   = (const float*)d_in[4];
  const float* g1   = (const float*)d_in[5];
  const float* be1  = (const float*)d_in[6];
  const float* Wl0  = (const float*)d_in[7];
  const float* bl0  = (const float*)d_in[8];
  const float* Wc   = (const float*)d_in[9];
  const float* bc   = (const float*)d_in[10];
  const float* g2   = (const float*)d_in[11];
  const float* be2  = (const float*)d_in[12];
  const float* Wl1  = (const float*)d_in[13];
  const float* bl1  = (const float*)d_in[14];

  float* out   = (float*)d_out;
  float* wsi   = out;                 // [8,4]
  float* npred = out + GG * TT;       // [N,4]

  ushort_t* h2bf   = (ushort_t*)d_ws;                 // N*H bf16 (h2)
  ushort_t* h1bf   = h2bf + (size_t)NN * HH;          // N*H bf16 (h1)
  uchar_t*  g8     = (uchar_t*)(h1bf + (size_t)NN * HH);   // N*H fp8 (g)
  float*    stats1 = (float*)(g8 + (size_t)NN * HH);  // 256
  float*    stats2 = stats1 + 256;                    // 256
  float*    maxb   = stats2 + 256;                    // 64
  int*      rowstart = (int*)(maxb + 64);             // N
  int*      Bcnt     = rowstart + NN;                 // 256
  int*      Bbase    = Bcnt + 256;                    // 256
  int*      srcl     = Bbase + 256;                   // NE+NN (self-loops)
  uint2*    ebuf     = (uint2*)(srcl + NTOT);         // NBK*BCAP pairs (16 MB)
  ushort_t* Wbf      = (ushort_t*)(ebuf + (size_t)NBK * BCAP);  // DF*HH
  ushort_t* Wbf2     = Wbf + DF * HH;                 // HH*HH

  // setup + bucketed CSR build
  k_setup<<<dim3(80), dim3(256), 0, stream>>>(Wf, Wbf, Wc, Wbf2, stats1, maxb, Bcnt);
  k_part<<<dim3(NPB), dim3(256), 0, stream>>>(ei, Bcnt, ebuf);
  k_bscan<<<dim3(1), dim3(256), 0, stream>>>(Bcnt, Bbase);
  k_fill2<<<dim3(NBK), dim3(256), 0, stream>>>(Bcnt, Bbase, ebuf, rowstart, srcl);

  // Layer 0: GEMM + stats (W in registers — proven config)
  k_gemm1_mfma<<<dim3(512), dim3(256), 0, stream>>>(x, Wbf, bf, h1bf, stats1);
  k_norm_gemm2<<<dim3(512), dim3(256), 0, stream>>>(
      h1bf, stats1, g1, be1, Wl0, bl0, bat, Wbf2, npred, maxb, g8);

  // Layer 1: h2 = b + g + A.g (2-deep pipelined flat-stream gather, fp8 rows)
  k_gather<<<dim3(NN / 32), dim3(256), 0, stream>>>(
      g8, rowstart, srcl, bc, h2bf, stats2);
  k_norm_np<<<dim3(512), dim3(256), 0, stream>>>(
      h2bf, stats2, g2, be2, Wl1, bl1, bat, npred, maxb + 32, (NN + 511) / 512);

  k_wsi<<<dim3(1), dim3(32), 0, stream>>>(maxb, maxb + 32, wsi);
}